// Round 5
// baseline (263.398 us; speedup 1.0000x reference)
//
#include <hip/hip_runtime.h>
#include <math.h>
#include <stdint.h>

#define NEXP 48
#define NCAT 30
#define SP_TOT 13440            // 24*28*20
#define M_TOT (NCAT * SP_TOT)   // 403200

// Two threads per column. Each sorts 24 |g| values (+8 pads) = 32 registers
// via a compile-time bitonic network; thread sub=1 stores NEGATED values so
// both threads run the identical ascending network (true-descending for
// sub=1). One uniform cross-lane merge step + a local ascending merge yields
// tau = 24th largest |g| in thread1's slot 23 (negated). Masked FMA with a
// boundary-tie count check; exact stable-rank (u64 key) fallback for ties
// and for K != 24 -- matches jax.lax.top_k semantics exactly.
__global__ __launch_bounds__(256, 6) void moe_topk_contract(
    const float* __restrict__ gm, const float* __restrict__ gf,
    const float* __restrict__ se, const int* __restrict__ kptr,
    float* __restrict__ out)
{
    const int tid = blockIdx.x * 256 + threadIdx.x;
    const int col = tid >> 1;     // voxel-column id
    const int sub = tid & 1;      // which half of the experts
    const int K   = *kptr;
    const float sgnf = sub ? -1.f : 1.f;

    #pragma unroll 1
    for (int t = 0; t < 2; ++t) {
        const float* __restrict__ g_    = t ? gf : gm;
        const float* __restrict__ gbase = g_ + (size_t)sub * 24 * M_TOT + col;
        const float* __restrict__ sbase = se + (size_t)sub * 24 * M_TOT + col;

        float tau = 0.f;
        if (K == 24) {
            float s[32];
            #pragma unroll
            for (int k = 0; k < 24; ++k)
                s[k] = sgnf * fabsf(gbase[k * M_TOT]);
            #pragma unroll
            for (int k = 24; k < 32; ++k)
                s[k] = sgnf * -INFINITY;      // true -inf pads

            // local bitonic sort, ascending in stored space (compile-time net)
            #pragma unroll
            for (int kk = 2; kk <= 32; kk <<= 1) {
                #pragma unroll
                for (int j = kk >> 1; j > 0; j >>= 1) {
                    #pragma unroll
                    for (int i = 0; i < 32; ++i) {
                        const int l = i ^ j;
                        if (l > i) {
                            const float lo = fminf(s[i], s[l]);
                            const float hi = fmaxf(s[i], s[l]);
                            if ((i & kk) == 0) { s[i] = lo; s[l] = hi; }
                            else               { s[i] = hi; s[l] = lo; }
                        }
                    }
                }
            }
            // cross-thread step of the 64-element merge (uniform both subs)
            #pragma unroll
            for (int k = 0; k < 32; ++k)
                s[k] = fminf(s[k], -__shfl_xor(s[k], 1));
            // local ascending bitonic merge (j = 16..1)
            #pragma unroll
            for (int j = 16; j > 0; j >>= 1) {
                #pragma unroll
                for (int i = 0; i < 32; ++i) {
                    const int l = i ^ j;
                    if (l > i) {
                        const float lo = fminf(s[i], s[l]);
                        s[l] = fmaxf(s[i], s[l]);
                        s[i] = lo;
                    }
                }
            }
            // tau lives in thread sub=1, slot 23 (stored negated)
            const float o23 = __shfl_xor(s[23], 1);
            tau = -(sub ? s[23] : o23);
        }

        // force re-load of g below (don't keep 24 copies alive across sort)
        asm volatile("" ::: "memory");

        float acc = 0.f;
        int cgt = 0, cge = 0;
        if (K == 24) {
            #pragma unroll
            for (int k = 0; k < 24; ++k) {
                const float gk = gbase[k * M_TOT];
                const float sk = sbase[k * M_TOT];
                const float a  = fabsf(gk);
                cgt += (a > tau)  ? 1 : 0;
                cge += (a >= tau) ? 1 : 0;
                acc = (a >= tau) ? fmaf(gk, sk, acc) : acc;
            }
            cgt += __shfl_xor(cgt, 1);
            cge += __shfl_xor(cge, 1);
        }

        const bool bad = (K != 24) || (cgt != 23) || (cge != 24);
        if (__any(bad)) {
            // exact stable-rank fallback (boundary |value| tie or generic K)
            if (bad) {
                acc = 0.f;
                if (sub == 0) {
                    #pragma unroll 1
                    for (int i2 = 0; i2 < NEXP; ++i2) {
                        const float gi = g_[i2 * M_TOT + col];
                        const uint64_t ki =
                            ((uint64_t)(__float_as_uint(gi) & 0x7fffffffu) << 32)
                            | (uint32_t)(NEXP - 1 - i2);
                        int r = 0;
                        #pragma unroll 1
                        for (int j2 = 0; j2 < NEXP; ++j2) {
                            const float gj = g_[j2 * M_TOT + col];
                            const uint64_t kj =
                                ((uint64_t)(__float_as_uint(gj) & 0x7fffffffu) << 32)
                                | (uint32_t)(NEXP - 1 - j2);
                            r += (kj > ki) ? 1 : 0;
                        }
                        if (r < K) acc = fmaf(gi, se[i2 * M_TOT + col], acc);
                    }
                }
            }
        }

        acc += __shfl_xor(acc, 1);
        if (sub == 0) out[t * M_TOT + col] = acc;
    }
}

// Kernel 2: in-place softmax over the category dim (stride SP_TOT).
__global__ __launch_bounds__(256) void softmax_c(float* __restrict__ out)
{
    const int q = blockIdx.x * blockDim.x + threadIdx.x;
    if (q >= 2 * SP_TOT) return;
    const int t  = q / SP_TOT;
    const int sp = q - t * SP_TOT;
    float* __restrict__ base = out + t * M_TOT + sp;

    float v[NCAT];
    float mx = -INFINITY;
    #pragma unroll
    for (int c = 0; c < NCAT; ++c) {
        v[c] = base[c * SP_TOT];
        mx = fmaxf(mx, v[c]);
    }
    float sum = 0.f;
    #pragma unroll
    for (int c = 0; c < NCAT; ++c) {
        v[c] = __expf(v[c] - mx);
        sum += v[c];
    }
    const float inv = 1.f / sum;
    #pragma unroll
    for (int c = 0; c < NCAT; ++c)
        base[c * SP_TOT] = v[c] * inv;
}

extern "C" void kernel_launch(void* const* d_in, const int* in_sizes, int n_in,
                              void* d_out, int out_size, void* d_ws, size_t ws_size,
                              hipStream_t stream) {
    const float* gm   = (const float*)d_in[0];
    const float* gf   = (const float*)d_in[1];
    const float* se   = (const float*)d_in[2];
    const int*   kptr = (const int*)d_in[3];
    float* out = (float*)d_out;

    const int grid1 = (M_TOT * 2) / 256;           // 3150 blocks, 2 thr/col
    moe_topk_contract<<<grid1, 256, 0, stream>>>(gm, gf, se, kptr, out);

    const int grid2 = (2 * SP_TOT + 255) / 256;    // 105
    softmax_c<<<grid2, 256, 0, stream>>>(out);
}

// Round 6
// 245.643 us; speedup vs baseline: 1.0723x; 1.0723x over previous
//
#include <hip/hip_runtime.h>
#include <math.h>
#include <stdint.h>

#define NEXP 48
#define NCAT 30
#define SP_TOT 13440            // 24*28*20
#define M_TOT (NCAT * SP_TOT)   // 403200
#define CPB 32                  // columns per block
#define PAD 49                  // LDS column stride (17c mod 32 -> bank-disjoint)

// r += (aj > ai) as exactly 2 VALU ops: v_cmp -> vcc, then add-with-carry.
__device__ __forceinline__ void rank_step(int& r, float aj, float ai) {
    asm("v_cmp_gt_f32 vcc, %1, %2\n\t"
        "v_addc_co_u32 %0, vcc, 0, %0, vcc"
        : "+v"(r) : "v"(aj), "v"(ai) : "vcc");
}

// R2 structure (proven 73% occ): 8 threads/col, 6 experts each, LDS-staged.
// Fast path: strict-|.| ranks via 2-instr asm pairs; exactness guaranteed by
// sum-of-ranks==C(48,2) tie detector + exact stable-rank (u64 key) fallback
// == jax.lax.top_k semantics. General in K.
__global__ __launch_bounds__(256) void moe_topk_contract(
    const float* __restrict__ gm, const float* __restrict__ gf,
    const float* __restrict__ se, const int* __restrict__ kptr,
    float* __restrict__ out)
{
    __shared__ float gv[CPB * PAD];

    const int tid     = threadIdx.x;
    const int colbase = blockIdx.x * CPB;
    const int cl      = tid >> 3;     // 0..31 column within block
    const int sub     = tid & 7;      // 0..7 expert sub-group
    const int col     = colbase + cl;
    const int K       = *kptr;

    // shape_experts for this thread's 6 experts (t-invariant, hoisted)
    float sev[6];
    #pragma unroll
    for (int ii = 0; ii < 6; ++ii)
        sev[ii] = se[(sub * 6 + ii) * M_TOT + col];

    #pragma unroll 1
    for (int t = 0; t < 2; ++t) {
        const float* __restrict__ g_ = t ? gf : gm;

        // stage raw f32: 48 experts x 32 cols, fully coalesced, bank-bijective
        #pragma unroll
        for (int rep = 0; rep < 6; ++rep) {
            const int e = rep * 8 + (tid >> 5);   // 0..47
            const int c = tid & 31;
            gv[c * PAD + e] = g_[e * M_TOT + colbase + c];
        }
        __syncthreads();

        // own 6 signed values + their abs
        float gval[6], a[6];
        #pragma unroll
        for (int ii = 0; ii < 6; ++ii) {
            gval[ii] = gv[cl * PAD + sub * 6 + ii];
            a[ii]    = fabsf(gval[ii]);
        }

        // strict-|.| rank: r[ii] = #{j: |g_j| > |g_ii|}, 2 VALU per pair
        int r0 = 0, r1 = 0, r2 = 0, r3 = 0, r4 = 0, r5 = 0;
        #pragma unroll 8
        for (int j = 0; j < NEXP; ++j) {
            const float aj = fabsf(gv[cl * PAD + j]);
            rank_step(r0, aj, a[0]);
            rank_step(r1, aj, a[1]);
            rank_step(r2, aj, a[2]);
            rank_step(r3, aj, a[3]);
            rank_step(r4, aj, a[4]);
            rank_step(r5, aj, a[5]);
        }

        // tie detection: distinct-|.| column <=> sum of strict ranks == 1128
        int S = r0 + r1 + r2 + r3 + r4 + r5;
        S += __shfl_xor(S, 1); S += __shfl_xor(S, 2); S += __shfl_xor(S, 4);
        const bool tie = (S != 1128);

        // masked contraction + 8-lane reduce
        const int rr[6] = {r0, r1, r2, r3, r4, r5};
        float acc = 0.f;
        #pragma unroll
        for (int ii = 0; ii < 6; ++ii)
            acc = (rr[ii] < K) ? fmaf(gval[ii], sev[ii], acc) : acc;
        acc += __shfl_xor(acc, 1); acc += __shfl_xor(acc, 2); acc += __shfl_xor(acc, 4);

        if (__any(tie)) {
            // exact stable-rank fallback (|value| tie in column; ~1e-7 of cols)
            if (tie && sub == 0) {
                float accx = 0.f;
                #pragma unroll 1
                for (int i2 = 0; i2 < NEXP; ++i2) {
                    const float gi = g_[i2 * M_TOT + col];
                    const uint64_t ki =
                        ((uint64_t)(__float_as_uint(gi) & 0x7fffffffu) << 32)
                        | (uint32_t)(NEXP - 1 - i2);
                    int rx = 0;
                    #pragma unroll 1
                    for (int j2 = 0; j2 < NEXP; ++j2) {
                        const float gj = g_[j2 * M_TOT + col];
                        const uint64_t kj =
                            ((uint64_t)(__float_as_uint(gj) & 0x7fffffffu) << 32)
                            | (uint32_t)(NEXP - 1 - j2);
                        rx += (kj > ki) ? 1 : 0;
                    }
                    if (rx < K) accx = fmaf(gi, se[i2 * M_TOT + col], accx);
                }
                acc = accx;
            }
        }

        if (sub == 0) out[t * M_TOT + col] = acc;
        __syncthreads();
    }
}

// Kernel 2: in-place softmax over the category dim (stride SP_TOT).
__global__ __launch_bounds__(256) void softmax_c(float* __restrict__ out)
{
    const int q = blockIdx.x * blockDim.x + threadIdx.x;
    if (q >= 2 * SP_TOT) return;
    const int t  = q / SP_TOT;
    const int sp = q - t * SP_TOT;
    float* __restrict__ base = out + t * M_TOT + sp;

    float v[NCAT];
    float mx = -INFINITY;
    #pragma unroll
    for (int c = 0; c < NCAT; ++c) {
        v[c] = base[c * SP_TOT];
        mx = fmaxf(mx, v[c]);
    }
    float sum = 0.f;
    #pragma unroll
    for (int c = 0; c < NCAT; ++c) {
        v[c] = __expf(v[c] - mx);
        sum += v[c];
    }
    const float inv = 1.f / sum;
    #pragma unroll
    for (int c = 0; c < NCAT; ++c)
        base[c * SP_TOT] = v[c] * inv;
}

extern "C" void kernel_launch(void* const* d_in, const int* in_sizes, int n_in,
                              void* d_out, int out_size, void* d_ws, size_t ws_size,
                              hipStream_t stream) {
    const float* gm   = (const float*)d_in[0];
    const float* gf   = (const float*)d_in[1];
    const float* se   = (const float*)d_in[2];
    const int*   kptr = (const int*)d_in[3];
    float* out = (float*)d_out;

    const int grid1 = M_TOT / CPB;                 // 12600
    moe_topk_contract<<<grid1, 256, 0, stream>>>(gm, gf, se, kptr, out);

    const int grid2 = (2 * SP_TOT + 255) / 256;    // 105
    softmax_c<<<grid2, 256, 0, stream>>>(out);
}

// Round 7
// 241.634 us; speedup vs baseline: 1.0901x; 1.0166x over previous
//
#include <hip/hip_runtime.h>
#include <math.h>
#include <stdint.h>

#define NEXP 48
#define NCAT 30
#define SP_TOT 13440            // 24*28*20
#define M_TOT (NCAT * SP_TOT)   // 403200
#define CPB 32                  // columns per block
#define PAD 50                  // words/col: float2-aligned; write stride 2-way (free); read groups bank-disjoint

// R2's proven structure: 8 threads/col, 6 experts each, 32 cols/block.
// LDS holds |g| (abs done once at stage time); rank loop is pure
// v_cmp_gt_f32 + addc (compiler-allocated carry regs -- no vcc pinning).
// Exactness: sum-of-strict-ranks == C(48,2) detector; any |value| tie falls
// back to exact stable u64-key ranks == jax.lax.top_k semantics. General K.
__global__ __launch_bounds__(256) void moe_topk_contract(
    const float* __restrict__ gm, const float* __restrict__ gf,
    const float* __restrict__ se, const int* __restrict__ kptr,
    float* __restrict__ out)
{
    __shared__ __align__(8) float ga[CPB * PAD];

    const int tid     = threadIdx.x;
    const int colbase = blockIdx.x * CPB;
    const int cl      = tid >> 3;     // 0..31 column within block
    const int sub     = tid & 7;      // 0..7 expert sub-group
    const int col     = colbase + cl;
    const int K       = *kptr;

    // shape_experts for this thread's 6 experts (t-invariant, hoisted)
    float sev[6];
    #pragma unroll
    for (int ii = 0; ii < 6; ++ii)
        sev[ii] = se[(sub * 6 + ii) * M_TOT + col];

    #pragma unroll 1
    for (int t = 0; t < 2; ++t) {
        const float* __restrict__ g_ = t ? gf : gm;

        // stage |g|: 48 experts x 32 cols, coalesced reads, abs once/element
        #pragma unroll
        for (int rep = 0; rep < 6; ++rep) {
            const int e = rep * 8 + (tid >> 5);   // 0..47
            const int c = tid & 31;
            ga[c * PAD + e] = fabsf(g_[e * M_TOT + colbase + c]);
        }
        __syncthreads();

        // own signed values from global (L1-hot: same lines as stage loads);
        // own abs from LDS (float2, no recompute)
        float gval[6], a[6];
        #pragma unroll
        for (int ii = 0; ii < 6; ++ii)
            gval[ii] = g_[(sub * 6 + ii) * M_TOT + col];
        #pragma unroll
        for (int p = 0; p < 3; ++p) {
            const float2 q = *(const float2*)&ga[cl * PAD + sub * 6 + p * 2];
            a[p * 2] = q.x; a[p * 2 + 1] = q.y;
        }

        // strict-|.| rank: r[ii] = #{j: |g_j| > |g_ii|}; plain C++ so the
        // compiler pipelines 6 independent cmp/addc streams.
        int r0 = 0, r1 = 0, r2 = 0, r3 = 0, r4 = 0, r5 = 0;
        #pragma unroll
        for (int j2 = 0; j2 < 24; ++j2) {
            const float2 q = *(const float2*)&ga[cl * PAD + j2 * 2];
            r0 += (q.x > a[0]); r0 += (q.y > a[0]);
            r1 += (q.x > a[1]); r1 += (q.y > a[1]);
            r2 += (q.x > a[2]); r2 += (q.y > a[2]);
            r3 += (q.x > a[3]); r3 += (q.y > a[3]);
            r4 += (q.x > a[4]); r4 += (q.y > a[4]);
            r5 += (q.x > a[5]); r5 += (q.y > a[5]);
        }

        // tie detection: all-|.|-distinct column <=> sum of strict ranks == 1128
        int S = r0 + r1 + r2 + r3 + r4 + r5;
        S += __shfl_xor(S, 1); S += __shfl_xor(S, 2); S += __shfl_xor(S, 4);
        const bool tie = (S != 1128);

        // masked contraction + 8-lane reduce
        const int rr[6] = {r0, r1, r2, r3, r4, r5};
        float acc = 0.f;
        #pragma unroll
        for (int ii = 0; ii < 6; ++ii) {
            const float mv = (rr[ii] < K) ? gval[ii] : 0.f;
            acc = fmaf(mv, sev[ii], acc);
        }
        acc += __shfl_xor(acc, 1); acc += __shfl_xor(acc, 2); acc += __shfl_xor(acc, 4);

        if (__any(tie)) {
            // exact stable-rank fallback (|value| tie in column; ~1e-7 of cols)
            if (tie && sub == 0) {
                float accx = 0.f;
                #pragma unroll 1
                for (int i2 = 0; i2 < NEXP; ++i2) {
                    const float gi = g_[i2 * M_TOT + col];
                    const uint64_t ki =
                        ((uint64_t)(__float_as_uint(gi) & 0x7fffffffu) << 32)
                        | (uint32_t)(NEXP - 1 - i2);
                    int rx = 0;
                    #pragma unroll 1
                    for (int j3 = 0; j3 < NEXP; ++j3) {
                        const float gj = g_[j3 * M_TOT + col];
                        const uint64_t kj =
                            ((uint64_t)(__float_as_uint(gj) & 0x7fffffffu) << 32)
                            | (uint32_t)(NEXP - 1 - j3);
                        rx += (kj > ki) ? 1 : 0;
                    }
                    if (rx < K) accx = fmaf(gi, se[i2 * M_TOT + col], accx);
                }
                acc = accx;
            }
        }

        if (sub == 0) out[t * M_TOT + col] = acc;
        __syncthreads();
    }
}

// Kernel 2: in-place softmax over the category dim (stride SP_TOT).
__global__ __launch_bounds__(256) void softmax_c(float* __restrict__ out)
{
    const int q = blockIdx.x * blockDim.x + threadIdx.x;
    if (q >= 2 * SP_TOT) return;
    const int t  = q / SP_TOT;
    const int sp = q - t * SP_TOT;
    float* __restrict__ base = out + t * M_TOT + sp;

    float v[NCAT];
    float mx = -INFINITY;
    #pragma unroll
    for (int c = 0; c < NCAT; ++c) {
        v[c] = base[c * SP_TOT];
        mx = fmaxf(mx, v[c]);
    }
    float sum = 0.f;
    #pragma unroll
    for (int c = 0; c < NCAT; ++c) {
        v[c] = __expf(v[c] - mx);
        sum += v[c];
    }
    const float inv = 1.f / sum;
    #pragma unroll
    for (int c = 0; c < NCAT; ++c)
        base[c * SP_TOT] = v[c] * inv;
}

extern "C" void kernel_launch(void* const* d_in, const int* in_sizes, int n_in,
                              void* d_out, int out_size, void* d_ws, size_t ws_size,
                              hipStream_t stream) {
    const float* gm   = (const float*)d_in[0];
    const float* gf   = (const float*)d_in[1];
    const float* se   = (const float*)d_in[2];
    const int*   kptr = (const int*)d_in[3];
    float* out = (float*)d_out;

    const int grid1 = M_TOT / CPB;                 // 12600
    moe_topk_contract<<<grid1, 256, 0, stream>>>(gm, gf, se, kptr, out);

    const int grid2 = (2 * SP_TOT + 255) / 256;    // 105
    softmax_c<<<grid2, 256, 0, stream>>>(out);
}

// Round 8
// 164.429 us; speedup vs baseline: 1.6019x; 1.4695x over previous
//
#include <hip/hip_runtime.h>
#include <math.h>
#include <stdint.h>

#define NEXP 48
#define NCAT 30
#define SP_TOT 13440            // 24*28*20
#define M_TOT (NCAT * SP_TOT)   // 403200

// Two threads per column (sub = tid&1 owns experts sub*24..sub*24+23).
// Each thread: load its 24 g values (kept in registers), bitonic-sort the
// 32-vector of |g| (+8 true -inf pads); sub=1 stores NEGATED values so both
// threads run the identical compile-time ascending network. One cross-lane
// merge step + local merge => tau = 24th largest |g| (verified in R5).
// Masked FMA straight from registers. Exactness: boundary-tie count check
// (cgt==23 && cge==24) -> rare exact stable u64-rank fallback == jax.lax.top_k.
__global__ __launch_bounds__(256) void moe_topk_contract(
    const float* __restrict__ gm, const float* __restrict__ gf,
    const float* __restrict__ se, const int* __restrict__ kptr,
    float* __restrict__ out)
{
    const int tid = blockIdx.x * 256 + threadIdx.x;
    const int col = tid >> 1;     // voxel-column id
    const int sub = tid & 1;      // expert half
    const int K   = *kptr;
    const float sgnf = sub ? -1.f : 1.f;

    #pragma unroll 1
    for (int t = 0; t < 2; ++t) {
        const float* __restrict__ g_    = t ? gf : gm;
        const float* __restrict__ gbase = g_ + (size_t)sub * 24 * M_TOT + col;
        const float* __restrict__ sbase = se + (size_t)sub * 24 * M_TOT + col;

        // own 24 gating values, kept live in registers through the sort
        float g[24];
        #pragma unroll
        for (int k = 0; k < 24; ++k) g[k] = gbase[k * M_TOT];

        float tau = 0.f;
        if (K == 24) {
            float s[32];
            #pragma unroll
            for (int k = 0; k < 24; ++k) s[k] = sgnf * fabsf(g[k]);
            #pragma unroll
            for (int k = 24; k < 32; ++k) s[k] = sgnf * -INFINITY;

            // local bitonic sort, ascending in stored space (compile-time net)
            #pragma unroll
            for (int kk = 2; kk <= 32; kk <<= 1) {
                #pragma unroll
                for (int j = kk >> 1; j > 0; j >>= 1) {
                    #pragma unroll
                    for (int i = 0; i < 32; ++i) {
                        const int l = i ^ j;
                        if (l > i) {
                            const float lo = fminf(s[i], s[l]);
                            const float hi = fmaxf(s[i], s[l]);
                            if ((i & kk) == 0) { s[i] = lo; s[l] = hi; }
                            else               { s[i] = hi; s[l] = lo; }
                        }
                    }
                }
            }
            // cross-thread step of the 64-element merge (uniform both subs)
            #pragma unroll
            for (int k = 0; k < 32; ++k)
                s[k] = fminf(s[k], -__shfl_xor(s[k], 1));
            // local ascending bitonic merge (j = 16..1)
            #pragma unroll
            for (int j = 16; j > 0; j >>= 1) {
                #pragma unroll
                for (int i = 0; i < 32; ++i) {
                    const int l = i ^ j;
                    if (l > i) {
                        const float lo = fminf(s[i], s[l]);
                        s[l] = fmaxf(s[i], s[l]);
                        s[i] = lo;
                    }
                }
            }
            // tau lives in thread sub=1, slot 23 (stored negated)
            const float o23 = __shfl_xor(s[23], 1);
            tau = -(sub ? s[23] : o23);
        }

        // masked contraction from registers + boundary-tie counts
        float acc = 0.f;
        int cgt = 0, cge = 0;
        if (K == 24) {
            #pragma unroll
            for (int k = 0; k < 24; ++k) {
                const float a  = fabsf(g[k]);
                const float sk = sbase[k * M_TOT];
                cgt += (a > tau)  ? 1 : 0;
                cge += (a >= tau) ? 1 : 0;
                const float mv = (a >= tau) ? g[k] : 0.f;
                acc = fmaf(mv, sk, acc);
            }
            cgt += __shfl_xor(cgt, 1);
            cge += __shfl_xor(cge, 1);
        }

        const bool bad = (K != 24) || (cgt != 23) || (cge != 24);
        if (__any(bad)) {
            // exact stable-rank fallback (boundary |value| tie or generic K)
            if (bad) {
                acc = 0.f;
                if (sub == 0) {
                    #pragma unroll 1
                    for (int i2 = 0; i2 < NEXP; ++i2) {
                        const float gi = g_[i2 * M_TOT + col];
                        const uint64_t ki =
                            ((uint64_t)(__float_as_uint(gi) & 0x7fffffffu) << 32)
                            | (uint32_t)(NEXP - 1 - i2);
                        int r = 0;
                        #pragma unroll 1
                        for (int j2 = 0; j2 < NEXP; ++j2) {
                            const float gj = g_[j2 * M_TOT + col];
                            const uint64_t kj =
                                ((uint64_t)(__float_as_uint(gj) & 0x7fffffffu) << 32)
                                | (uint32_t)(NEXP - 1 - j2);
                            r += (kj > ki) ? 1 : 0;
                        }
                        if (r < K) acc = fmaf(gi, se[i2 * M_TOT + col], acc);
                    }
                }
            }
        }

        acc += __shfl_xor(acc, 1);
        if (sub == 0) out[t * M_TOT + col] = acc;
    }
}

// Kernel 2: in-place softmax over the category dim (stride SP_TOT).
__global__ __launch_bounds__(256) void softmax_c(float* __restrict__ out)
{
    const int q = blockIdx.x * blockDim.x + threadIdx.x;
    if (q >= 2 * SP_TOT) return;
    const int t  = q / SP_TOT;
    const int sp = q - t * SP_TOT;
    float* __restrict__ base = out + t * M_TOT + sp;

    float v[NCAT];
    float mx = -INFINITY;
    #pragma unroll
    for (int c = 0; c < NCAT; ++c) {
        v[c] = base[c * SP_TOT];
        mx = fmaxf(mx, v[c]);
    }
    float sum = 0.f;
    #pragma unroll
    for (int c = 0; c < NCAT; ++c) {
        v[c] = __expf(v[c] - mx);
        sum += v[c];
    }
    const float inv = 1.f / sum;
    #pragma unroll
    for (int c = 0; c < NCAT; ++c)
        base[c * SP_TOT] = v[c] * inv;
}

extern "C" void kernel_launch(void* const* d_in, const int* in_sizes, int n_in,
                              void* d_out, int out_size, void* d_ws, size_t ws_size,
                              hipStream_t stream) {
    const float* gm   = (const float*)d_in[0];
    const float* gf   = (const float*)d_in[1];
    const float* se   = (const float*)d_in[2];
    const int*   kptr = (const int*)d_in[3];
    float* out = (float*)d_out;

    const int grid1 = (M_TOT * 2) / 256;           // 3150 blocks, 2 thr/col
    moe_topk_contract<<<grid1, 256, 0, stream>>>(gm, gf, se, kptr, out);

    const int grid2 = (2 * SP_TOT + 255) / 256;    // 105
    softmax_c<<<grid2, 256, 0, stream>>>(out);
}